// Round 13
// baseline (137.479 us; speedup 1.0000x reference)
//
#include <hip/hip_runtime.h>

// ---------------------------------------------------------------------------
// BetterGooLayer R13: identical resubmit of R12 (container died before bench).
// R12: software-pipelined pair blocks. R11 post-mortem: sim at 3.0 TB/s (hf:
// 5.2) with VALU 12% — memory duty-cycle bound: 8KB/wave load burst at block
// start, then memory-silent compute. R12: block = (bm, d-pair), chain 1's
// loads issued during chain 0's compute (prefetch-to-registers), 2 barriers
// per block. Per-chain math/scan/rebase identical to R11 (absmax 16).
// ---------------------------------------------------------------------------

#define NS    8192
#define BB    4
#define MM    64
#define DD    8
#define NF    8
#define FL    256
#define DAMP  0.9998f
#define SEG   2048

#define REC_OFF  0
#define DISP_OFF (BB*MM*NS)                 // 2097152
#define HF_OFF   (DISP_OFF + BB*MM*DD*NS)   // 18874368

#define SW(i) ((i) + ((i) >> 5))

struct Mat { float a, b, c, d; };
__device__ __forceinline__ Mat matmul(Mat x, Mat y) {
    Mat r;
    r.a = fmaf(x.a, y.a, x.b * y.c);
    r.b = fmaf(x.a, y.b, x.b * y.d);
    r.c = fmaf(x.c, y.a, x.d * y.c);
    r.d = fmaf(x.c, y.b, x.d * y.d);
    return r;
}

// ---------------- threefry2x32 (JAX, partitionable counters) ----------------
__device__ __forceinline__ unsigned rotl32(unsigned x, int r) {
    return (x << r) | (x >> (32 - r));
}
__device__ float jax_noise(unsigned idx) {
    const unsigned ks0 = 0u;
    const unsigned ks1 = 123u;
    const unsigned ks2 = 0x1BD11BDAu ^ 0u ^ 123u;
    unsigned x0 = 0u  + ks0;
    unsigned x1 = idx + ks1;
#define TF_RND(r) { x0 += x1; x1 = rotl32(x1, r); x1 ^= x0; }
    TF_RND(13) TF_RND(15) TF_RND(26) TF_RND(6)
    x0 += ks1; x1 += ks2 + 1u;
    TF_RND(17) TF_RND(29) TF_RND(16) TF_RND(24)
    x0 += ks2; x1 += ks0 + 2u;
    TF_RND(13) TF_RND(15) TF_RND(26) TF_RND(6)
    x0 += ks0; x1 += ks1 + 3u;
    TF_RND(17) TF_RND(29) TF_RND(16) TF_RND(24)
    x0 += ks1; x1 += ks2 + 4u;
    TF_RND(13) TF_RND(15) TF_RND(26) TF_RND(6)
    x0 += ks2; x1 += ks0 + 5u;
#undef TF_RND
    unsigned bits = x0 ^ x1;
    float u = __uint_as_float((bits >> 9) | 0x3f800000u) - 1.0f;  // [0,1)
    return fmaxf(-0.01f, u * 0.02f - 0.01f);
}

// ---------------- fused sim: block = (bm, d-pair), 512 threads --------------
__global__ __launch_bounds__(512, 6) void sim_fused(
    const float* __restrict__ forces, const float* __restrict__ hm,
    const float* __restrict__ home,   const float* __restrict__ cs,
    const float* __restrict__ masses, const float* __restrict__ tens,
    const float* __restrict__ mics,   float* __restrict__ out,
    float* __restrict__ part)
{
    __shared__ __align__(16) float sbuf[8][1280];   // 40 KB wave-local
    __shared__ float2 qcL[2][64];

    int bmp  = blockIdx.x;          // bm*4 + p
    int bm   = bmp >> 2;
    int p    = bmp & 3;
    int tid  = threadIdx.x;
    int wl   = tid >> 6;
    int lane = tid & 63;
    int sub  = lane & 7;
    int m    = bm & (MM - 1);

    float ms  = masses[m];
    float csm = cs[m];

    float* sb = sbuf[wl];
    int wp = (lane >> 2) * 20 + (lane & 3) * 4;

    size_t g0 = (size_t)(bm * DD + 2 * p) * NS + wl * 1024;
    size_t g1 = g0 + NS;    // chain d = 2p+1

    // ---- chain 0 loads ----
    float4 a0 = *(const float4*)(forces + g0 +   0 + 4 * lane);
    float4 a1 = *(const float4*)(forces + g0 + 256 + 4 * lane);
    float4 a2 = *(const float4*)(forces + g0 + 512 + 4 * lane);
    float4 a3 = *(const float4*)(forces + g0 + 768 + 4 * lane);
    float4 b0 = *(const float4*)(hm + g0 +   0 + 4 * lane);
    float4 b1 = *(const float4*)(hm + g0 + 256 + 4 * lane);
    float4 b2 = *(const float4*)(hm + g0 + 512 + 4 * lane);
    float4 b3 = *(const float4*)(hm + g0 + 768 + 4 * lane);

    // transpose f0 -> regs
    *(float4*)(sb + wp +   0) = a0;
    *(float4*)(sb + wp + 320) = a1;
    *(float4*)(sb + wp + 640) = a2;
    *(float4*)(sb + wp + 960) = a3;
    float4 fq[4];
#pragma unroll
    for (int q = 0; q < 4; ++q)
        fq[q] = *(const float4*)(sb + lane * 20 + 4 * q);
    // transpose h0 -> LDS
    *(float4*)(sb + wp +   0) = b0;
    *(float4*)(sb + wp + 320) = b1;
    *(float4*)(sb + wp + 640) = b2;
    *(float4*)(sb + wp + 960) = b3;

    // ---- issue chain 1 loads NOW (in flight during chain-0 compute) ----
    float4 c0 = *(const float4*)(forces + g1 +   0 + 4 * lane);
    float4 c1 = *(const float4*)(forces + g1 + 256 + 4 * lane);
    float4 c2 = *(const float4*)(forces + g1 + 512 + 4 * lane);
    float4 c3 = *(const float4*)(forces + g1 + 768 + 4 * lane);
    float4 e0 = *(const float4*)(hm + g1 +   0 + 4 * lane);
    float4 e1 = *(const float4*)(hm + g1 + 256 + 4 * lane);
    float4 e2 = *(const float4*)(hm + g1 + 512 + 4 * lane);
    float4 e3 = *(const float4*)(hm + g1 + 768 + 4 * lane);

    // ================== chain 0 compute ==================
    {
        int d = 2 * p;
        float k   = tens[m * DD + d] / ms;
        float hd  = home[d];
        float mm_ = ms * mics[m * DD + d];

        float dir0[16];
        float pos = 0.f, vel = 0.f;
#pragma unroll
        for (int q = 0; q < 4; ++q) {
            float4 hv = *(const float4*)(sb + lane * 20 + 4 * q);
            float hh[4] = {hv.x, hv.y, hv.z, hv.w};
            const float* frq = (const float*)&fq[q];
#pragma unroll
            for (int i = 0; i < 4; ++i) {
                float ht = fmaf(hh[i], csm, hd);
                float u  = fmaf(k, ht, frq[i]);
                dir0[q * 4 + i] = ht - pos;
                float w  = fmaf(-k, pos, u);
                vel = (vel + w) * DAMP;
                pos += vel;
            }
        }
        float Wx = pos, Wy = vel;

        Mat A   = {1.f - DAMP * k, DAMP, -DAMP * k, DAMP};
        Mat A2  = matmul(A, A);
        Mat A4  = matmul(A2, A2);
        Mat A8  = matmul(A4, A4);
        Mat M0  = matmul(A8, A8);
        Mat M1  = matmul(M0, M0);
        Mat M2  = matmul(M1, M1);
        Mat P = {1.f, 0.f, 0.f, 1.f};
        if (sub & 1) P = matmul(P, M0);
        if (sub & 2) P = matmul(P, M1);
        if (sub & 4) P = matmul(P, M2);

        {
            float ox, oy;
            ox = __shfl_up(Wx, 1, 64); oy = __shfl_up(Wy, 1, 64);
            if (sub >= 1) { float nx = Wx + fmaf(M0.a, ox, M0.b * oy);
                            float ny = Wy + fmaf(M0.c, ox, M0.d * oy);
                            Wx = nx; Wy = ny; }
            ox = __shfl_up(Wx, 2, 64); oy = __shfl_up(Wy, 2, 64);
            if (sub >= 2) { float nx = Wx + fmaf(M1.a, ox, M1.b * oy);
                            float ny = Wy + fmaf(M1.c, ox, M1.d * oy);
                            Wx = nx; Wy = ny; }
            ox = __shfl_up(Wx, 4, 64); oy = __shfl_up(Wy, 4, 64);
            if (sub >= 4) { float nx = Wx + fmaf(M2.a, ox, M2.b * oy);
                            float ny = Wy + fmaf(M2.c, ox, M2.d * oy);
                            Wx = nx; Wy = ny; }
        }
        float Ex = __shfl_up(Wx, 1, 64);
        float Ey = __shfl_up(Wy, 1, 64);
        if (sub == 0) { Ex = 0.f; Ey = 0.f; }
        if (sub == 7) qcL[0][tid >> 3] = make_float2(Wx, Wy);

        __syncthreads();

        float s0x, s0y;
        {
            Mat B = matmul(M2, M2);
            float2 qv = qcL[0][lane];
            float sx = qv.x, sy = qv.y;
            Mat Kr = B;
#pragma unroll
            for (int r = 0; r < 6; ++r) {
                float ox = __shfl_up(sx, 1 << r, 64);
                float oy = __shfl_up(sy, 1 << r, 64);
                if (lane >= (1 << r)) {
                    float nx = fmaf(Kr.a, ox, fmaf(Kr.b, oy, sx));
                    float ny = fmaf(Kr.c, ox, fmaf(Kr.d, oy, sy));
                    sx = nx; sy = ny;
                }
                if (r < 5) Kr = matmul(Kr, Kr);
            }
            int srcl = (tid >> 3) - 1;
            float px = __shfl(sx, srcl & 63, 64);
            float py = __shfl(sy, srcl & 63, 64);
            if (srcl < 0) { px = 0.f; py = 0.f; }
            s0x = px; s0y = py;
        }

        float ex = fmaf(P.a, s0x, fmaf(P.b, s0y, Ex));
        float ey = fmaf(P.c, s0x, fmaf(P.d, s0y, Ey));

        float rv[16];
#pragma unroll
        for (int q = 0; q < 4; ++q) {
            float dv[4];
            const float* frq = (const float*)&fq[q];
#pragma unroll
            for (int i = 0; i < 4; ++i) {
                int j = q * 4 + i;
                float dir = dir0[j] - ex;
                float acc = fmaf(k, dir, frq[i]);
                dv[i] = dir;
                rv[j] = mm_ * acc;
                float nx = fmaf(A.a, ex, A.b * ey);
                float ny = fmaf(A.c, ex, A.d * ey);
                ex = nx; ey = ny;
            }
            *(float4*)(sb + lane * 20 + 4 * q) =
                make_float4(dv[0], dv[1], dv[2], dv[3]);
        }
#pragma unroll
        for (int i = 0; i < 4; ++i) {
            float4 v = *(const float4*)(sb + wp + i * 320);
            *(float4*)(out + DISP_OFF + g0 + i * 256 + 4 * lane) = v;
        }
#pragma unroll
        for (int q = 0; q < 4; ++q)
            *(float4*)(sb + lane * 20 + 4 * q) =
                make_float4(rv[q*4], rv[q*4+1], rv[q*4+2], rv[q*4+3]);
#pragma unroll
        for (int i = 0; i < 4; ++i) {
            float4 v = *(const float4*)(sb + wp + i * 320);
            *(float4*)(part + g0 + i * 256 + 4 * lane) = v;
        }
    }

    // ================== chain 1 compute ==================
    // transpose f1 -> regs
    *(float4*)(sb + wp +   0) = c0;
    *(float4*)(sb + wp + 320) = c1;
    *(float4*)(sb + wp + 640) = c2;
    *(float4*)(sb + wp + 960) = c3;
    float4 fq1[4];
#pragma unroll
    for (int q = 0; q < 4; ++q)
        fq1[q] = *(const float4*)(sb + lane * 20 + 4 * q);
    // transpose h1 -> LDS
    *(float4*)(sb + wp +   0) = e0;
    *(float4*)(sb + wp + 320) = e1;
    *(float4*)(sb + wp + 640) = e2;
    *(float4*)(sb + wp + 960) = e3;

    {
        int d = 2 * p + 1;
        float k   = tens[m * DD + d] / ms;
        float hd  = home[d];
        float mm_ = ms * mics[m * DD + d];

        float dir0[16];
        float pos = 0.f, vel = 0.f;
#pragma unroll
        for (int q = 0; q < 4; ++q) {
            float4 hv = *(const float4*)(sb + lane * 20 + 4 * q);
            float hh[4] = {hv.x, hv.y, hv.z, hv.w};
            const float* frq = (const float*)&fq1[q];
#pragma unroll
            for (int i = 0; i < 4; ++i) {
                float ht = fmaf(hh[i], csm, hd);
                float u  = fmaf(k, ht, frq[i]);
                dir0[q * 4 + i] = ht - pos;
                float w  = fmaf(-k, pos, u);
                vel = (vel + w) * DAMP;
                pos += vel;
            }
        }
        float Wx = pos, Wy = vel;

        Mat A   = {1.f - DAMP * k, DAMP, -DAMP * k, DAMP};
        Mat A2  = matmul(A, A);
        Mat A4  = matmul(A2, A2);
        Mat A8  = matmul(A4, A4);
        Mat M0  = matmul(A8, A8);
        Mat M1  = matmul(M0, M0);
        Mat M2  = matmul(M1, M1);
        Mat P = {1.f, 0.f, 0.f, 1.f};
        if (sub & 1) P = matmul(P, M0);
        if (sub & 2) P = matmul(P, M1);
        if (sub & 4) P = matmul(P, M2);

        {
            float ox, oy;
            ox = __shfl_up(Wx, 1, 64); oy = __shfl_up(Wy, 1, 64);
            if (sub >= 1) { float nx = Wx + fmaf(M0.a, ox, M0.b * oy);
                            float ny = Wy + fmaf(M0.c, ox, M0.d * oy);
                            Wx = nx; Wy = ny; }
            ox = __shfl_up(Wx, 2, 64); oy = __shfl_up(Wy, 2, 64);
            if (sub >= 2) { float nx = Wx + fmaf(M1.a, ox, M1.b * oy);
                            float ny = Wy + fmaf(M1.c, ox, M1.d * oy);
                            Wx = nx; Wy = ny; }
            ox = __shfl_up(Wx, 4, 64); oy = __shfl_up(Wy, 4, 64);
            if (sub >= 4) { float nx = Wx + fmaf(M2.a, ox, M2.b * oy);
                            float ny = Wy + fmaf(M2.c, ox, M2.d * oy);
                            Wx = nx; Wy = ny; }
        }
        float Ex = __shfl_up(Wx, 1, 64);
        float Ey = __shfl_up(Wy, 1, 64);
        if (sub == 0) { Ex = 0.f; Ey = 0.f; }
        if (sub == 7) qcL[1][tid >> 3] = make_float2(Wx, Wy);

        __syncthreads();

        float s0x, s0y;
        {
            Mat B = matmul(M2, M2);
            float2 qv = qcL[1][lane];
            float sx = qv.x, sy = qv.y;
            Mat Kr = B;
#pragma unroll
            for (int r = 0; r < 6; ++r) {
                float ox = __shfl_up(sx, 1 << r, 64);
                float oy = __shfl_up(sy, 1 << r, 64);
                if (lane >= (1 << r)) {
                    float nx = fmaf(Kr.a, ox, fmaf(Kr.b, oy, sx));
                    float ny = fmaf(Kr.c, ox, fmaf(Kr.d, oy, sy));
                    sx = nx; sy = ny;
                }
                if (r < 5) Kr = matmul(Kr, Kr);
            }
            int srcl = (tid >> 3) - 1;
            float px = __shfl(sx, srcl & 63, 64);
            float py = __shfl(sy, srcl & 63, 64);
            if (srcl < 0) { px = 0.f; py = 0.f; }
            s0x = px; s0y = py;
        }

        float ex = fmaf(P.a, s0x, fmaf(P.b, s0y, Ex));
        float ey = fmaf(P.c, s0x, fmaf(P.d, s0y, Ey));

        float rv[16];
#pragma unroll
        for (int q = 0; q < 4; ++q) {
            float dv[4];
            const float* frq = (const float*)&fq1[q];
#pragma unroll
            for (int i = 0; i < 4; ++i) {
                int j = q * 4 + i;
                float dir = dir0[j] - ex;
                float acc = fmaf(k, dir, frq[i]);
                dv[i] = dir;
                rv[j] = mm_ * acc;
                float nx = fmaf(A.a, ex, A.b * ey);
                float ny = fmaf(A.c, ex, A.d * ey);
                ex = nx; ey = ny;
            }
            *(float4*)(sb + lane * 20 + 4 * q) =
                make_float4(dv[0], dv[1], dv[2], dv[3]);
        }
#pragma unroll
        for (int i = 0; i < 4; ++i) {
            float4 v = *(const float4*)(sb + wp + i * 320);
            *(float4*)(out + DISP_OFF + g1 + i * 256 + 4 * lane) = v;
        }
#pragma unroll
        for (int q = 0; q < 4; ++q)
            *(float4*)(sb + lane * 20 + 4 * q) =
                make_float4(rv[q*4], rv[q*4+1], rv[q*4+2], rv[q*4+3]);
#pragma unroll
        for (int i = 0; i < 4; ++i) {
            float4 v = *(const float4*)(sb + wp + i * 320);
            *(float4*)(part + g1 + i * 256 + 4 * lane) = v;
        }
    }
}

// ---------------- HF kernel: 8-partial sum + noise + FIR + rec/hf write -----
__global__ __launch_bounds__(256) void hf_kernel(
    const float* __restrict__ part,
    const float* __restrict__ filters, const float* __restrict__ tfm,
    const float* __restrict__ bias,    const float* __restrict__ hf_gain,
    float* __restrict__ out)
{
    __shared__ float up[SW(FL + SEG) + 8];
    __shared__ float recL[SEG];
    __shared__ float gtap[FL];
    int bm  = blockIdx.x >> 2;
    int seg = blockIdx.x & 3;
    int b = bm >> 6;
    int m = bm & 63;
    int tx = threadIdx.x;
    int T0 = seg * SEG;

    float gs = 0.f;
#pragma unroll
    for (int f = 0; f < NF; ++f) {
        float mix = 0.f;
#pragma unroll
        for (int dd = 0; dd < DD; ++dd)
            mix = fmaf(bias[m * DD + dd], tfm[(m * DD + dd) * NF + f], mix);
        gs = fmaf(mix, filters[(b * NF + f) * FL + tx], gs);
    }
    gtap[tx] = gs;

    const float* pb = part + (size_t)(bm * DD) * NS;
    for (int j = tx; j < FL + SEG; j += 256) {
        int t = T0 - FL + j;
        float v = 0.f, r = 0.f;
        if (t >= 0) {
            r = ((pb[t] + pb[t + NS]) + (pb[t + 2 * NS] + pb[t + 3 * NS]))
              + ((pb[t + 4 * NS] + pb[t + 5 * NS])
               + (pb[t + 6 * NS] + pb[t + 7 * NS]));
            v = fabsf(r) * jax_noise((unsigned)(bm * NS + t));
        }
        up[SW(j)] = v;
        if (j >= FL) recL[j - FL] = r;
    }
    __syncthreads();

    float gain = hf_gain[0];
    int t0 = tx * 8;
    float acc[8] = {0, 0, 0, 0, 0, 0, 0, 0};
    float w[8];
#pragma unroll
    for (int j = 0; j < 8; ++j) w[j] = up[SW(t0 + 1 + j)];
#pragma unroll 8
    for (int s = 255; s >= 1; --s) {
        float gv = gtap[s];
#pragma unroll
        for (int j = 0; j < 8; ++j) acc[j] = fmaf(gv, w[j], acc[j]);
#pragma unroll
        for (int j = 0; j < 7; ++j) w[j] = w[j + 1];
        w[7] = up[SW(FL + t0 + 8 - s)];
    }
    float g0 = gtap[0];
#pragma unroll
    for (int j = 0; j < 8; ++j) acc[j] = fmaf(g0, w[j], acc[j]);
    float4 r0 = *(const float4*)(&recL[t0]);
    float4 r1 = *(const float4*)(&recL[t0 + 4]);
    float4 o0 = make_float4(fmaf(gain, acc[0], r0.x), fmaf(gain, acc[1], r0.y),
                            fmaf(gain, acc[2], r0.z), fmaf(gain, acc[3], r0.w));
    float4 o1 = make_float4(fmaf(gain, acc[4], r1.x), fmaf(gain, acc[5], r1.y),
                            fmaf(gain, acc[6], r1.z), fmaf(gain, acc[7], r1.w));
    size_t rowoff = (size_t)bm * NS + T0 + t0;
    *(float4*)(out + HF_OFF + rowoff)     = o0;
    *(float4*)(out + HF_OFF + rowoff + 4) = o1;
    *(float4*)(out + REC_OFF + rowoff)     = r0;
    *(float4*)(out + REC_OFF + rowoff + 4) = r1;
}

extern "C" void kernel_launch(void* const* d_in, const int* in_sizes, int n_in,
                              void* d_out, int out_size, void* d_ws, size_t ws_size,
                              hipStream_t stream)
{
    const float* forces  = (const float*)d_in[0];
    const float* hm      = (const float*)d_in[1];
    const float* filters = (const float*)d_in[2];
    const float* home    = (const float*)d_in[3];
    const float* cs      = (const float*)d_in[4];
    const float* masses  = (const float*)d_in[5];
    const float* tens    = (const float*)d_in[6];
    const float* mics    = (const float*)d_in[7];
    const float* tfm     = (const float*)d_in[8];
    const float* bias    = (const float*)d_in[9];
    const float* gain    = (const float*)d_in[10];
    float* out = (float*)d_out;

    float* part = (float*)d_ws;    // 2048 rows x 8192 floats = 64 MiB

    sim_fused<<<BB * MM * 4, 512, 0, stream>>>(
        forces, hm, home, cs, masses, tens, mics, out, part);
    hf_kernel<<<BB * MM * 4, 256, 0, stream>>>(
        part, filters, tfm, bias, gain, out);
}

// Round 14
// 116.779 us; speedup vs baseline: 1.1773x; 1.1773x over previous
//
#include <hip/hip_runtime.h>

// ---------------------------------------------------------------------------
// BetterGooLayer R14: "naked" sim — no LDS staging at all.
// R13 post-mortem: register prefetch spilled to scratch (FETCH +46MB, WRITE
// +88MB at fixed VGPR=40) — regression. R10 (LDS-transposed, 74us sim) is the
// base. R14 removes the transposes entirely: thread tid owns steps
// [tid*16,tid*16+16); 64B-lane-stride dwordx4 loads/stores have no HBM
// amplification (R6 vs R7: scattered == transposed). Registers only; LDS =
// qcL (512B); one barrier; R11-validated math (walk1+dir0, f32 scans, linear
// correction). Occupancy cap 28 waves/CU via launch_bounds(512,7).
// ---------------------------------------------------------------------------

#define NS    8192
#define BB    4
#define MM    64
#define DD    8
#define NF    8
#define FL    256
#define DAMP  0.9998f
#define SEG   2048

#define REC_OFF  0
#define DISP_OFF (BB*MM*NS)                 // 2097152
#define HF_OFF   (DISP_OFF + BB*MM*DD*NS)   // 18874368

#define SW(i) ((i) + ((i) >> 5))

struct Mat { float a, b, c, d; };
__device__ __forceinline__ Mat matmul(Mat x, Mat y) {
    Mat r;
    r.a = fmaf(x.a, y.a, x.b * y.c);
    r.b = fmaf(x.a, y.b, x.b * y.d);
    r.c = fmaf(x.c, y.a, x.d * y.c);
    r.d = fmaf(x.c, y.b, x.d * y.d);
    return r;
}

// ---------------- threefry2x32 (JAX, partitionable counters) ----------------
__device__ __forceinline__ unsigned rotl32(unsigned x, int r) {
    return (x << r) | (x >> (32 - r));
}
__device__ float jax_noise(unsigned idx) {
    const unsigned ks0 = 0u;
    const unsigned ks1 = 123u;
    const unsigned ks2 = 0x1BD11BDAu ^ 0u ^ 123u;
    unsigned x0 = 0u  + ks0;
    unsigned x1 = idx + ks1;
#define TF_RND(r) { x0 += x1; x1 = rotl32(x1, r); x1 ^= x0; }
    TF_RND(13) TF_RND(15) TF_RND(26) TF_RND(6)
    x0 += ks1; x1 += ks2 + 1u;
    TF_RND(17) TF_RND(29) TF_RND(16) TF_RND(24)
    x0 += ks2; x1 += ks0 + 2u;
    TF_RND(13) TF_RND(15) TF_RND(26) TF_RND(6)
    x0 += ks0; x1 += ks1 + 3u;
    TF_RND(17) TF_RND(29) TF_RND(16) TF_RND(24)
    x0 += ks1; x1 += ks2 + 4u;
    TF_RND(13) TF_RND(15) TF_RND(26) TF_RND(6)
    x0 += ks2; x1 += ks0 + 5u;
#undef TF_RND
    unsigned bits = x0 ^ x1;
    float u = __uint_as_float((bits >> 9) | 0x3f800000u) - 1.0f;  // [0,1)
    return fmaxf(-0.01f, u * 0.02f - 0.01f);
}

// ---------------- fused sim: block = (bm,d) chain, 512 threads, no staging --
__global__ __launch_bounds__(512, 7) void sim_fused(
    const float* __restrict__ forces, const float* __restrict__ hm,
    const float* __restrict__ home,   const float* __restrict__ cs,
    const float* __restrict__ masses, const float* __restrict__ tens,
    const float* __restrict__ mics,   float* __restrict__ out,
    float* __restrict__ part)
{
    __shared__ float2 qcL[64];

    int bmd  = blockIdx.x;          // bm*8 + d
    int bm   = bmd >> 3;
    int d    = bmd & 7;
    int tid  = threadIdx.x;
    int sub  = tid & 7;             // position within 8-thread chunk octet
    int m    = bm & (MM - 1);

    float ms  = masses[m];
    float k   = tens[m * DD + d] / ms;
    float csm = cs[m];
    float hd  = home[d];
    float mm_ = ms * mics[m * DD + d];

    size_t gbase = (size_t)bmd * NS + tid * 16;

    // direct loads: thread's own 16 steps (64B per array, 64B lane stride)
    float4 fq[4], hq[4];
#pragma unroll
    for (int q = 0; q < 4; ++q) {
        fq[q] = *(const float4*)(forces + gbase + q * 4);
        hq[q] = *(const float4*)(hm + gbase + q * 4);
    }
    const float* fr = (const float*)fq;
    const float* hr = (const float*)hq;

    // walk1 from zero state (u-form), capture dir0[16]; h dies here
    float dir0[16];
    float pos = 0.f, vel = 0.f;
#pragma unroll
    for (int j = 0; j < 16; ++j) {
        float ht = fmaf(hr[j], csm, hd);
        float u  = fmaf(k, ht, fr[j]);
        dir0[j]  = ht - pos;
        float w  = fmaf(-k, pos, u);
        vel = (vel + w) * DAMP;
        pos += vel;
    }
    float Wx = pos, Wy = vel;

    Mat A   = {1.f - DAMP * k, DAMP, -DAMP * k, DAMP};
    Mat A2  = matmul(A, A);
    Mat A4  = matmul(A2, A2);
    Mat A8  = matmul(A4, A4);
    Mat M0  = matmul(A8, A8);      // A^16
    Mat M1  = matmul(M0, M0);      // A^32
    Mat M2  = matmul(M1, M1);      // A^64
    Mat P = {1.f, 0.f, 0.f, 1.f};  // (A^16)^sub
    if (sub & 1) P = matmul(P, M0);
    if (sub & 2) P = matmul(P, M1);
    if (sub & 4) P = matmul(P, M2);

    // octet Kogge-Stone (f32) within 8-lane groups
    {
        float ox, oy;
        ox = __shfl_up(Wx, 1, 64); oy = __shfl_up(Wy, 1, 64);
        if (sub >= 1) { float nx = Wx + fmaf(M0.a, ox, M0.b * oy);
                        float ny = Wy + fmaf(M0.c, ox, M0.d * oy);
                        Wx = nx; Wy = ny; }
        ox = __shfl_up(Wx, 2, 64); oy = __shfl_up(Wy, 2, 64);
        if (sub >= 2) { float nx = Wx + fmaf(M1.a, ox, M1.b * oy);
                        float ny = Wy + fmaf(M1.c, ox, M1.d * oy);
                        Wx = nx; Wy = ny; }
        ox = __shfl_up(Wx, 4, 64); oy = __shfl_up(Wy, 4, 64);
        if (sub >= 4) { float nx = Wx + fmaf(M2.a, ox, M2.b * oy);
                        float ny = Wy + fmaf(M2.c, ox, M2.d * oy);
                        Wx = nx; Wy = ny; }
    }
    float Ex = __shfl_up(Wx, 1, 64);
    float Ey = __shfl_up(Wy, 1, 64);
    if (sub == 0) { Ex = 0.f; Ey = 0.f; }
    if (sub == 7) qcL[tid >> 3] = make_float2(Wx, Wy);

    __syncthreads();   // the ONLY block barrier

    // f32 chunk scan over 64 chunks, redundantly in every wave (lane = chunk)
    float s0x, s0y;
    {
        int lane = tid & 63;
        Mat B = matmul(M2, M2);     // A^128
        float2 qv = qcL[lane];
        float sx = qv.x, sy = qv.y;
        Mat Kr = B;
#pragma unroll
        for (int r = 0; r < 6; ++r) {
            float ox = __shfl_up(sx, 1 << r, 64);
            float oy = __shfl_up(sy, 1 << r, 64);
            if (lane >= (1 << r)) {
                float nx = fmaf(Kr.a, ox, fmaf(Kr.b, oy, sx));
                float ny = fmaf(Kr.c, ox, fmaf(Kr.d, oy, sy));
                sx = nx; sy = ny;
            }
            if (r < 5) Kr = matmul(Kr, Kr);
        }
        int srcl = (tid >> 3) - 1;
        float px = __shfl(sx, srcl & 63, 64);
        float py = __shfl(sy, srcl & 63, 64);
        if (srcl < 0) { px = 0.f; py = 0.f; }
        s0x = px; s0y = py;
    }

    // window-start state, then linear correction pass (no rewalk)
    float ex = fmaf(P.a, s0x, fmaf(P.b, s0y, Ex));
    float ey = fmaf(P.c, s0x, fmaf(P.d, s0y, Ey));

#pragma unroll
    for (int q = 0; q < 4; ++q) {
        float dv[4], rv[4];
#pragma unroll
        for (int i = 0; i < 4; ++i) {
            int j = q * 4 + i;
            float dir = dir0[j] - ex;                 // dir = dir0 - [A^j s]x
            float acc = fmaf(k, dir, fr[j]);          // reference-exact form
            dv[i] = dir;
            rv[i] = mm_ * acc;
            float nx = fmaf(A.a, ex, A.b * ey);       // e <- A e
            float ny = fmaf(A.c, ex, A.d * ey);
            ex = nx; ey = ny;
        }
        *(float4*)(out + DISP_OFF + gbase + q * 4) =
            make_float4(dv[0], dv[1], dv[2], dv[3]);
        *(float4*)(part + gbase + q * 4) =
            make_float4(rv[0], rv[1], rv[2], rv[3]);
    }
}

// ---------------- HF kernel: 8-partial sum + noise + FIR + rec/hf write -----
__global__ __launch_bounds__(256) void hf_kernel(
    const float* __restrict__ part,
    const float* __restrict__ filters, const float* __restrict__ tfm,
    const float* __restrict__ bias,    const float* __restrict__ hf_gain,
    float* __restrict__ out)
{
    __shared__ float up[SW(FL + SEG) + 8];
    __shared__ float recL[SEG];
    __shared__ float gtap[FL];
    int bm  = blockIdx.x >> 2;
    int seg = blockIdx.x & 3;
    int b = bm >> 6;
    int m = bm & 63;
    int tx = threadIdx.x;
    int T0 = seg * SEG;

    float gs = 0.f;
#pragma unroll
    for (int f = 0; f < NF; ++f) {
        float mix = 0.f;
#pragma unroll
        for (int dd = 0; dd < DD; ++dd)
            mix = fmaf(bias[m * DD + dd], tfm[(m * DD + dd) * NF + f], mix);
        gs = fmaf(mix, filters[(b * NF + f) * FL + tx], gs);
    }
    gtap[tx] = gs;

    const float* pb = part + (size_t)(bm * DD) * NS;
    for (int j = tx; j < FL + SEG; j += 256) {
        int t = T0 - FL + j;
        float v = 0.f, r = 0.f;
        if (t >= 0) {
            r = ((pb[t] + pb[t + NS]) + (pb[t + 2 * NS] + pb[t + 3 * NS]))
              + ((pb[t + 4 * NS] + pb[t + 5 * NS])
               + (pb[t + 6 * NS] + pb[t + 7 * NS]));
            v = fabsf(r) * jax_noise((unsigned)(bm * NS + t));
        }
        up[SW(j)] = v;
        if (j >= FL) recL[j - FL] = r;
    }
    __syncthreads();

    float gain = hf_gain[0];
    int t0 = tx * 8;
    float acc[8] = {0, 0, 0, 0, 0, 0, 0, 0};
    float w[8];
#pragma unroll
    for (int j = 0; j < 8; ++j) w[j] = up[SW(t0 + 1 + j)];
#pragma unroll 8
    for (int s = 255; s >= 1; --s) {
        float gv = gtap[s];
#pragma unroll
        for (int j = 0; j < 8; ++j) acc[j] = fmaf(gv, w[j], acc[j]);
#pragma unroll
        for (int j = 0; j < 7; ++j) w[j] = w[j + 1];
        w[7] = up[SW(FL + t0 + 8 - s)];
    }
    float g0 = gtap[0];
#pragma unroll
    for (int j = 0; j < 8; ++j) acc[j] = fmaf(g0, w[j], acc[j]);
    float4 r0 = *(const float4*)(&recL[t0]);
    float4 r1 = *(const float4*)(&recL[t0 + 4]);
    float4 o0 = make_float4(fmaf(gain, acc[0], r0.x), fmaf(gain, acc[1], r0.y),
                            fmaf(gain, acc[2], r0.z), fmaf(gain, acc[3], r0.w));
    float4 o1 = make_float4(fmaf(gain, acc[4], r1.x), fmaf(gain, acc[5], r1.y),
                            fmaf(gain, acc[6], r1.z), fmaf(gain, acc[7], r1.w));
    size_t rowoff = (size_t)bm * NS + T0 + t0;
    *(float4*)(out + HF_OFF + rowoff)     = o0;
    *(float4*)(out + HF_OFF + rowoff + 4) = o1;
    *(float4*)(out + REC_OFF + rowoff)     = r0;
    *(float4*)(out + REC_OFF + rowoff + 4) = r1;
}

extern "C" void kernel_launch(void* const* d_in, const int* in_sizes, int n_in,
                              void* d_out, int out_size, void* d_ws, size_t ws_size,
                              hipStream_t stream)
{
    const float* forces  = (const float*)d_in[0];
    const float* hm      = (const float*)d_in[1];
    const float* filters = (const float*)d_in[2];
    const float* home    = (const float*)d_in[3];
    const float* cs      = (const float*)d_in[4];
    const float* masses  = (const float*)d_in[5];
    const float* tens    = (const float*)d_in[6];
    const float* mics    = (const float*)d_in[7];
    const float* tfm     = (const float*)d_in[8];
    const float* bias    = (const float*)d_in[9];
    const float* gain    = (const float*)d_in[10];
    float* out = (float*)d_out;

    float* part = (float*)d_ws;    // 2048 rows x 8192 floats = 64 MiB

    sim_fused<<<BB * MM * DD, 512, 0, stream>>>(
        forces, hm, home, cs, masses, tens, mics, out, part);
    hf_kernel<<<BB * MM * 4, 256, 0, stream>>>(
        part, filters, tfm, bias, gain, out);
}

// Round 16
// 96.866 us; speedup vs baseline: 1.4193x; 1.2056x over previous
//
#include <hip/hip_runtime.h>

// ---------------------------------------------------------------------------
// BetterGooLayer R16: identical resubmit of R15 (container died before bench).
// R15: naked sim with allocator-friendly register budget. R14 spilled
// (VGPR=36 vs ~56 live) under launch_bounds(512,7) -> scratch traffic.
// R15/R16: 1024 thr x 8 steps/thread (16-lane group per 128-step chunk, same
// rebase cadence); persistent regs across barrier = fr[8]+dir0[8];
// launch_bounds(1024,4) so the allocator is unconstrained. LDS = qcL only;
// one barrier; R11-validated math.
// ---------------------------------------------------------------------------

#define NS    8192
#define BB    4
#define MM    64
#define DD    8
#define NF    8
#define FL    256
#define DAMP  0.9998f
#define SEG   2048

#define REC_OFF  0
#define DISP_OFF (BB*MM*NS)                 // 2097152
#define HF_OFF   (DISP_OFF + BB*MM*DD*NS)   // 18874368

#define SW(i) ((i) + ((i) >> 5))

struct Mat { float a, b, c, d; };
__device__ __forceinline__ Mat matmul(Mat x, Mat y) {
    Mat r;
    r.a = fmaf(x.a, y.a, x.b * y.c);
    r.b = fmaf(x.a, y.b, x.b * y.d);
    r.c = fmaf(x.c, y.a, x.d * y.c);
    r.d = fmaf(x.c, y.b, x.d * y.d);
    return r;
}

// ---------------- threefry2x32 (JAX, partitionable counters) ----------------
__device__ __forceinline__ unsigned rotl32(unsigned x, int r) {
    return (x << r) | (x >> (32 - r));
}
__device__ float jax_noise(unsigned idx) {
    const unsigned ks0 = 0u;
    const unsigned ks1 = 123u;
    const unsigned ks2 = 0x1BD11BDAu ^ 0u ^ 123u;
    unsigned x0 = 0u  + ks0;
    unsigned x1 = idx + ks1;
#define TF_RND(r) { x0 += x1; x1 = rotl32(x1, r); x1 ^= x0; }
    TF_RND(13) TF_RND(15) TF_RND(26) TF_RND(6)
    x0 += ks1; x1 += ks2 + 1u;
    TF_RND(17) TF_RND(29) TF_RND(16) TF_RND(24)
    x0 += ks2; x1 += ks0 + 2u;
    TF_RND(13) TF_RND(15) TF_RND(26) TF_RND(6)
    x0 += ks0; x1 += ks1 + 3u;
    TF_RND(17) TF_RND(29) TF_RND(16) TF_RND(24)
    x0 += ks1; x1 += ks2 + 4u;
    TF_RND(13) TF_RND(15) TF_RND(26) TF_RND(6)
    x0 += ks2; x1 += ks0 + 5u;
#undef TF_RND
    unsigned bits = x0 ^ x1;
    float u = __uint_as_float((bits >> 9) | 0x3f800000u) - 1.0f;  // [0,1)
    return fmaxf(-0.01f, u * 0.02f - 0.01f);
}

// ---------------- fused sim: block = (bm,d) chain, 1024 thr x 8 steps -------
__global__ __launch_bounds__(1024, 4) void sim_fused(
    const float* __restrict__ forces, const float* __restrict__ hm,
    const float* __restrict__ home,   const float* __restrict__ cs,
    const float* __restrict__ masses, const float* __restrict__ tens,
    const float* __restrict__ mics,   float* __restrict__ out,
    float* __restrict__ part)
{
    __shared__ float2 qcL[64];

    int bmd  = blockIdx.x;          // bm*8 + d
    int bm   = bmd >> 3;
    int d    = bmd & 7;
    int tid  = threadIdx.x;
    int sub  = tid & 15;            // position within 16-thread chunk group
    int m    = bm & (MM - 1);

    float ms  = masses[m];
    float k   = tens[m * DD + d] / ms;
    float csm = cs[m];
    float hd  = home[d];
    float mm_ = ms * mics[m * DD + d];

    size_t gbase = (size_t)bmd * NS + tid * 8;

    // direct loads: thread's own 8 steps (32B per array)
    float4 fq[2], hq[2];
    fq[0] = *(const float4*)(forces + gbase);
    fq[1] = *(const float4*)(forces + gbase + 4);
    hq[0] = *(const float4*)(hm + gbase);
    hq[1] = *(const float4*)(hm + gbase + 4);
    const float* fr = (const float*)fq;
    const float* hr = (const float*)hq;

    // walk1 from zero state (u-form), capture dir0[8]; h dies here
    float dir0[8];
    float pos = 0.f, vel = 0.f;
#pragma unroll
    for (int j = 0; j < 8; ++j) {
        float ht = fmaf(hr[j], csm, hd);
        float u  = fmaf(k, ht, fr[j]);
        dir0[j]  = ht - pos;
        float w  = fmaf(-k, pos, u);
        vel = (vel + w) * DAMP;
        pos += vel;
    }
    float Wx = pos, Wy = vel;

    Mat A   = {1.f - DAMP * k, DAMP, -DAMP * k, DAMP};
    Mat A2  = matmul(A, A);
    Mat A4  = matmul(A2, A2);
    Mat G0  = matmul(A4, A4);      // A^8
    Mat G1  = matmul(G0, G0);      // A^16
    Mat G2  = matmul(G1, G1);      // A^32
    Mat G3  = matmul(G2, G2);      // A^64
    Mat P = {1.f, 0.f, 0.f, 1.f};  // (A^8)^sub
    if (sub & 1) P = matmul(P, G0);
    if (sub & 2) P = matmul(P, G1);
    if (sub & 4) P = matmul(P, G2);
    if (sub & 8) P = matmul(P, G3);

    // 16-lane Kogge-Stone (f32) within chunk groups
    {
        float ox, oy;
        ox = __shfl_up(Wx, 1, 64); oy = __shfl_up(Wy, 1, 64);
        if (sub >= 1) { float nx = Wx + fmaf(G0.a, ox, G0.b * oy);
                        float ny = Wy + fmaf(G0.c, ox, G0.d * oy);
                        Wx = nx; Wy = ny; }
        ox = __shfl_up(Wx, 2, 64); oy = __shfl_up(Wy, 2, 64);
        if (sub >= 2) { float nx = Wx + fmaf(G1.a, ox, G1.b * oy);
                        float ny = Wy + fmaf(G1.c, ox, G1.d * oy);
                        Wx = nx; Wy = ny; }
        ox = __shfl_up(Wx, 4, 64); oy = __shfl_up(Wy, 4, 64);
        if (sub >= 4) { float nx = Wx + fmaf(G2.a, ox, G2.b * oy);
                        float ny = Wy + fmaf(G2.c, ox, G2.d * oy);
                        Wx = nx; Wy = ny; }
        ox = __shfl_up(Wx, 8, 64); oy = __shfl_up(Wy, 8, 64);
        if (sub >= 8) { float nx = Wx + fmaf(G3.a, ox, G3.b * oy);
                        float ny = Wy + fmaf(G3.c, ox, G3.d * oy);
                        Wx = nx; Wy = ny; }
    }
    float Ex = __shfl_up(Wx, 1, 64);
    float Ey = __shfl_up(Wy, 1, 64);
    if (sub == 0) { Ex = 0.f; Ey = 0.f; }
    if (sub == 15) qcL[tid >> 4] = make_float2(Wx, Wy);

    __syncthreads();   // the ONLY block barrier

    // f32 chunk scan over 64 chunks, redundantly per wave (lane = chunk)
    float s0x, s0y;
    {
        int lane = tid & 63;
        Mat B = matmul(G3, G3);     // A^128
        float2 qv = qcL[lane];
        float sx = qv.x, sy = qv.y;
        Mat Kr = B;
#pragma unroll
        for (int r = 0; r < 6; ++r) {
            float ox = __shfl_up(sx, 1 << r, 64);
            float oy = __shfl_up(sy, 1 << r, 64);
            if (lane >= (1 << r)) {
                float nx = fmaf(Kr.a, ox, fmaf(Kr.b, oy, sx));
                float ny = fmaf(Kr.c, ox, fmaf(Kr.d, oy, sy));
                sx = nx; sy = ny;
            }
            if (r < 5) Kr = matmul(Kr, Kr);
        }
        int srcc = (tid >> 4) - 1;
        float px = __shfl(sx, srcc & 63, 64);
        float py = __shfl(sy, srcc & 63, 64);
        if (srcc < 0) { px = 0.f; py = 0.f; }
        s0x = px; s0y = py;
    }

    // window-start state, then linear correction pass (no rewalk)
    float ex = fmaf(P.a, s0x, fmaf(P.b, s0y, Ex));
    float ey = fmaf(P.c, s0x, fmaf(P.d, s0y, Ey));

#pragma unroll
    for (int q = 0; q < 2; ++q) {
        float dv[4], rv[4];
#pragma unroll
        for (int i = 0; i < 4; ++i) {
            int j = q * 4 + i;
            float dir = dir0[j] - ex;                 // dir = dir0 - [A^j s]x
            float acc = fmaf(k, dir, fr[j]);          // reference-exact form
            dv[i] = dir;
            rv[i] = mm_ * acc;
            float nx = fmaf(A.a, ex, A.b * ey);       // e <- A e
            float ny = fmaf(A.c, ex, A.d * ey);
            ex = nx; ey = ny;
        }
        *(float4*)(out + DISP_OFF + gbase + q * 4) =
            make_float4(dv[0], dv[1], dv[2], dv[3]);
        *(float4*)(part + gbase + q * 4) =
            make_float4(rv[0], rv[1], rv[2], rv[3]);
    }
}

// ---------------- HF kernel: 8-partial sum + noise + FIR + rec/hf write -----
__global__ __launch_bounds__(256) void hf_kernel(
    const float* __restrict__ part,
    const float* __restrict__ filters, const float* __restrict__ tfm,
    const float* __restrict__ bias,    const float* __restrict__ hf_gain,
    float* __restrict__ out)
{
    __shared__ float up[SW(FL + SEG) + 8];
    __shared__ float recL[SEG];
    __shared__ float gtap[FL];
    int bm  = blockIdx.x >> 2;
    int seg = blockIdx.x & 3;
    int b = bm >> 6;
    int m = bm & 63;
    int tx = threadIdx.x;
    int T0 = seg * SEG;

    float gs = 0.f;
#pragma unroll
    for (int f = 0; f < NF; ++f) {
        float mix = 0.f;
#pragma unroll
        for (int dd = 0; dd < DD; ++dd)
            mix = fmaf(bias[m * DD + dd], tfm[(m * DD + dd) * NF + f], mix);
        gs = fmaf(mix, filters[(b * NF + f) * FL + tx], gs);
    }
    gtap[tx] = gs;

    const float* pb = part + (size_t)(bm * DD) * NS;
    for (int j = tx; j < FL + SEG; j += 256) {
        int t = T0 - FL + j;
        float v = 0.f, r = 0.f;
        if (t >= 0) {
            r = ((pb[t] + pb[t + NS]) + (pb[t + 2 * NS] + pb[t + 3 * NS]))
              + ((pb[t + 4 * NS] + pb[t + 5 * NS])
               + (pb[t + 6 * NS] + pb[t + 7 * NS]));
            v = fabsf(r) * jax_noise((unsigned)(bm * NS + t));
        }
        up[SW(j)] = v;
        if (j >= FL) recL[j - FL] = r;
    }
    __syncthreads();

    float gain = hf_gain[0];
    int t0 = tx * 8;
    float acc[8] = {0, 0, 0, 0, 0, 0, 0, 0};
    float w[8];
#pragma unroll
    for (int j = 0; j < 8; ++j) w[j] = up[SW(t0 + 1 + j)];
#pragma unroll 8
    for (int s = 255; s >= 1; --s) {
        float gv = gtap[s];
#pragma unroll
        for (int j = 0; j < 8; ++j) acc[j] = fmaf(gv, w[j], acc[j]);
#pragma unroll
        for (int j = 0; j < 7; ++j) w[j] = w[j + 1];
        w[7] = up[SW(FL + t0 + 8 - s)];
    }
    float g0 = gtap[0];
#pragma unroll
    for (int j = 0; j < 8; ++j) acc[j] = fmaf(g0, w[j], acc[j]);
    float4 r0 = *(const float4*)(&recL[t0]);
    float4 r1 = *(const float4*)(&recL[t0 + 4]);
    float4 o0 = make_float4(fmaf(gain, acc[0], r0.x), fmaf(gain, acc[1], r0.y),
                            fmaf(gain, acc[2], r0.z), fmaf(gain, acc[3], r0.w));
    float4 o1 = make_float4(fmaf(gain, acc[4], r1.x), fmaf(gain, acc[5], r1.y),
                            fmaf(gain, acc[6], r1.z), fmaf(gain, acc[7], r1.w));
    size_t rowoff = (size_t)bm * NS + T0 + t0;
    *(float4*)(out + HF_OFF + rowoff)     = o0;
    *(float4*)(out + HF_OFF + rowoff + 4) = o1;
    *(float4*)(out + REC_OFF + rowoff)     = r0;
    *(float4*)(out + REC_OFF + rowoff + 4) = r1;
}

extern "C" void kernel_launch(void* const* d_in, const int* in_sizes, int n_in,
                              void* d_out, int out_size, void* d_ws, size_t ws_size,
                              hipStream_t stream)
{
    const float* forces  = (const float*)d_in[0];
    const float* hm      = (const float*)d_in[1];
    const float* filters = (const float*)d_in[2];
    const float* home    = (const float*)d_in[3];
    const float* cs      = (const float*)d_in[4];
    const float* masses  = (const float*)d_in[5];
    const float* tens    = (const float*)d_in[6];
    const float* mics    = (const float*)d_in[7];
    const float* tfm     = (const float*)d_in[8];
    const float* bias    = (const float*)d_in[9];
    const float* gain    = (const float*)d_in[10];
    float* out = (float*)d_out;

    float* part = (float*)d_ws;    // 2048 rows x 8192 floats = 64 MiB

    sim_fused<<<BB * MM * DD, 1024, 0, stream>>>(
        forces, hm, home, cs, masses, tens, mics, out, part);
    hf_kernel<<<BB * MM * 4, 256, 0, stream>>>(
        part, filters, tfm, bias, gain, out);
}

// Round 17
// 64.788 us; speedup vs baseline: 2.1220x; 1.4951x over previous
//
#include <hip/hip_runtime.h>

// ---------------------------------------------------------------------------
// BetterGooLayer R17: single fully-fused kernel.
// R16 post-mortem: sim time == (own 197MB + harness poison-drain 327MB) /
// 6.8TB/s exactly -> HBM-bound incl. fixed drain. Only lever: own bytes.
// R17: block = bm, 8-chain loop; thread owns time slice [tid*8,tid*8+8) for
// ALL chains -> rec d-reduction is a register accumulation (no part buffer:
// -67MB W, -67MB R) and the FIR runs in the same block from LDS (no hf
// kernel). Per-chain math identical to R16 (walk1+dir0, group/chunk f32 KS,
// linear correction). 1 barrier/chain + 2 for FIR. LDS 37KB. VGPR cap 128.
// ---------------------------------------------------------------------------

#define NS    8192
#define BB    4
#define MM    64
#define DD    8
#define NF    8
#define FL    256
#define DAMP  0.9998f

#define REC_OFF  0
#define DISP_OFF (BB*MM*NS)                 // 2097152
#define HF_OFF   (DISP_OFF + BB*MM*DD*NS)   // 18874368

#define SW(i) ((i) + ((i) >> 5))

struct Mat { float a, b, c, d; };
__device__ __forceinline__ Mat matmul(Mat x, Mat y) {
    Mat r;
    r.a = fmaf(x.a, y.a, x.b * y.c);
    r.b = fmaf(x.a, y.b, x.b * y.d);
    r.c = fmaf(x.c, y.a, x.d * y.c);
    r.d = fmaf(x.c, y.b, x.d * y.d);
    return r;
}

// ---------------- threefry2x32 (JAX, partitionable counters) ----------------
__device__ __forceinline__ unsigned rotl32(unsigned x, int r) {
    return (x << r) | (x >> (32 - r));
}
__device__ float jax_noise(unsigned idx) {
    const unsigned ks0 = 0u;
    const unsigned ks1 = 123u;
    const unsigned ks2 = 0x1BD11BDAu ^ 0u ^ 123u;
    unsigned x0 = 0u  + ks0;
    unsigned x1 = idx + ks1;
#define TF_RND(r) { x0 += x1; x1 = rotl32(x1, r); x1 ^= x0; }
    TF_RND(13) TF_RND(15) TF_RND(26) TF_RND(6)
    x0 += ks1; x1 += ks2 + 1u;
    TF_RND(17) TF_RND(29) TF_RND(16) TF_RND(24)
    x0 += ks2; x1 += ks0 + 2u;
    TF_RND(13) TF_RND(15) TF_RND(26) TF_RND(6)
    x0 += ks0; x1 += ks1 + 3u;
    TF_RND(17) TF_RND(29) TF_RND(16) TF_RND(24)
    x0 += ks1; x1 += ks2 + 4u;
    TF_RND(13) TF_RND(15) TF_RND(26) TF_RND(6)
    x0 += ks2; x1 += ks0 + 5u;
#undef TF_RND
    unsigned bits = x0 ^ x1;
    float u = __uint_as_float((bits >> 9) | 0x3f800000u) - 1.0f;  // [0,1)
    return fmaxf(-0.01f, u * 0.02f - 0.01f);
}

// ---------------- fused everything: block = bm, 1024 threads ----------------
__global__ __launch_bounds__(1024, 4) void sim_all(
    const float* __restrict__ forces, const float* __restrict__ hm,
    const float* __restrict__ home,   const float* __restrict__ cs,
    const float* __restrict__ masses, const float* __restrict__ tens,
    const float* __restrict__ mics,
    const float* __restrict__ filters, const float* __restrict__ tfm,
    const float* __restrict__ bias,    const float* __restrict__ hf_gain,
    float* __restrict__ out)
{
    __shared__ float up[SW(FL + NS) + 8];   // ~34.8 KB noise window
    __shared__ float gtap[FL];
    __shared__ float2 qcL[2][64];

    int bm   = blockIdx.x;
    int tid  = threadIdx.x;
    int sub  = tid & 15;            // position within 16-thread chunk group
    int m    = bm & (MM - 1);

    float ms  = masses[m];
    float csm = cs[m];

    size_t chbase = (size_t)(bm * DD) * NS + tid * 8;

    float rec_acc[8] = {0, 0, 0, 0, 0, 0, 0, 0};

    // prologue: chain 0 loads
    float4 fq[2], hq[2];
    fq[0] = *(const float4*)(forces + chbase);
    fq[1] = *(const float4*)(forces + chbase + 4);
    hq[0] = *(const float4*)(hm + chbase);
    hq[1] = *(const float4*)(hm + chbase + 4);

    for (int d = 0; d < DD; ++d) {
        float k   = tens[m * DD + d] / ms;
        float hd  = home[d];
        float mm_ = ms * mics[m * DD + d];
        size_t gbase = chbase + (size_t)d * NS;

        const float* fr = (const float*)fq;
        const float* hr = (const float*)hq;

        // walk1 from zero state (u-form), capture dir0[8]; h dies here
        float dir0[8];
        float pos = 0.f, vel = 0.f;
#pragma unroll
        for (int j = 0; j < 8; ++j) {
            float ht = fmaf(hr[j], csm, hd);
            float u  = fmaf(k, ht, fr[j]);
            dir0[j]  = ht - pos;
            float w  = fmaf(-k, pos, u);
            vel = (vel + w) * DAMP;
            pos += vel;
        }
        float Wx = pos, Wy = vel;

        // prefetch next chain (hq dead; fq still live for correction)
        float4 nf0, nf1, nh0, nh1;
        if (d + 1 < DD) {
            size_t gn = gbase + NS;
            nf0 = *(const float4*)(forces + gn);
            nf1 = *(const float4*)(forces + gn + 4);
            nh0 = *(const float4*)(hm + gn);
            nh1 = *(const float4*)(hm + gn + 4);
        }

        Mat A   = {1.f - DAMP * k, DAMP, -DAMP * k, DAMP};
        Mat A2  = matmul(A, A);
        Mat A4  = matmul(A2, A2);
        Mat G0  = matmul(A4, A4);      // A^8
        Mat G1  = matmul(G0, G0);      // A^16
        Mat G2  = matmul(G1, G1);      // A^32
        Mat G3  = matmul(G2, G2);      // A^64
        Mat P = {1.f, 0.f, 0.f, 1.f};  // (A^8)^sub
        if (sub & 1) P = matmul(P, G0);
        if (sub & 2) P = matmul(P, G1);
        if (sub & 4) P = matmul(P, G2);
        if (sub & 8) P = matmul(P, G3);

        // 16-lane Kogge-Stone (f32) within chunk groups
        {
            float ox, oy;
            ox = __shfl_up(Wx, 1, 64); oy = __shfl_up(Wy, 1, 64);
            if (sub >= 1) { float nx = Wx + fmaf(G0.a, ox, G0.b * oy);
                            float ny = Wy + fmaf(G0.c, ox, G0.d * oy);
                            Wx = nx; Wy = ny; }
            ox = __shfl_up(Wx, 2, 64); oy = __shfl_up(Wy, 2, 64);
            if (sub >= 2) { float nx = Wx + fmaf(G1.a, ox, G1.b * oy);
                            float ny = Wy + fmaf(G1.c, ox, G1.d * oy);
                            Wx = nx; Wy = ny; }
            ox = __shfl_up(Wx, 4, 64); oy = __shfl_up(Wy, 4, 64);
            if (sub >= 4) { float nx = Wx + fmaf(G2.a, ox, G2.b * oy);
                            float ny = Wy + fmaf(G2.c, ox, G2.d * oy);
                            Wx = nx; Wy = ny; }
            ox = __shfl_up(Wx, 8, 64); oy = __shfl_up(Wy, 8, 64);
            if (sub >= 8) { float nx = Wx + fmaf(G3.a, ox, G3.b * oy);
                            float ny = Wy + fmaf(G3.c, ox, G3.d * oy);
                            Wx = nx; Wy = ny; }
        }
        float Ex = __shfl_up(Wx, 1, 64);
        float Ey = __shfl_up(Wy, 1, 64);
        if (sub == 0) { Ex = 0.f; Ey = 0.f; }
        if (sub == 15) qcL[d & 1][tid >> 4] = make_float2(Wx, Wy);

        __syncthreads();   // one barrier per chain

        // f32 chunk scan over 64 chunks, redundantly per wave (lane = chunk)
        float s0x, s0y;
        {
            int lane = tid & 63;
            Mat B = matmul(G3, G3);     // A^128
            float2 qv = qcL[d & 1][lane];
            float sx = qv.x, sy = qv.y;
            Mat Kr = B;
#pragma unroll
            for (int r = 0; r < 6; ++r) {
                float ox = __shfl_up(sx, 1 << r, 64);
                float oy = __shfl_up(sy, 1 << r, 64);
                if (lane >= (1 << r)) {
                    float nx = fmaf(Kr.a, ox, fmaf(Kr.b, oy, sx));
                    float ny = fmaf(Kr.c, ox, fmaf(Kr.d, oy, sy));
                    sx = nx; sy = ny;
                }
                if (r < 5) Kr = matmul(Kr, Kr);
            }
            int srcc = (tid >> 4) - 1;
            float px = __shfl(sx, srcc & 63, 64);
            float py = __shfl(sy, srcc & 63, 64);
            if (srcc < 0) { px = 0.f; py = 0.f; }
            s0x = px; s0y = py;
        }

        // window-start state, then linear correction pass
        float ex = fmaf(P.a, s0x, fmaf(P.b, s0y, Ex));
        float ey = fmaf(P.c, s0x, fmaf(P.d, s0y, Ey));

#pragma unroll
        for (int q = 0; q < 2; ++q) {
            float dv[4];
#pragma unroll
            for (int i = 0; i < 4; ++i) {
                int j = q * 4 + i;
                float dir = dir0[j] - ex;                 // dir = dir0 - [A^j s]x
                float acc = fmaf(k, dir, fr[j]);          // reference-exact
                dv[i] = dir;
                rec_acc[j] = fmaf(mm_, acc, rec_acc[j]);  // d-reduction in regs
                float nx = fmaf(A.a, ex, A.b * ey);       // e <- A e
                float ny = fmaf(A.c, ex, A.d * ey);
                ex = nx; ey = ny;
            }
            *(float4*)(out + DISP_OFF + gbase + q * 4) =
                make_float4(dv[0], dv[1], dv[2], dv[3]);
        }

        if (d + 1 < DD) {
            fq[0] = nf0; fq[1] = nf1;
            hq[0] = nh0; hq[1] = nh1;
        }
    }

    // ---- rec output + noise window + combined filter taps ----
    size_t rowbase = (size_t)bm * NS + tid * 8;
    *(float4*)(out + REC_OFF + rowbase) =
        make_float4(rec_acc[0], rec_acc[1], rec_acc[2], rec_acc[3]);
    *(float4*)(out + REC_OFF + rowbase + 4) =
        make_float4(rec_acc[4], rec_acc[5], rec_acc[6], rec_acc[7]);

    int t0 = tid * 8;
#pragma unroll
    for (int i = 0; i < 8; ++i) {
        float nz = jax_noise((unsigned)(bm * NS + t0 + i));
        up[SW(FL + t0 + i)] = fabsf(rec_acc[i]) * nz;
    }
    if (tid < FL) {
        up[SW(tid)] = 0.f;     // left pad (t < 0)
        int b = bm >> 6;
        float gs = 0.f;
#pragma unroll
        for (int f = 0; f < NF; ++f) {
            float mix = 0.f;
#pragma unroll
            for (int dd = 0; dd < DD; ++dd)
                mix = fmaf(bias[m * DD + dd], tfm[(m * DD + dd) * NF + f], mix);
            gs = fmaf(mix, filters[(b * NF + f) * FL + tid], gs);
        }
        gtap[tid] = gs;
    }
    __syncthreads();

    // ---- FIR: 8 outputs per thread, register sliding window ----
    float gain = hf_gain[0];
    float acc[8] = {0, 0, 0, 0, 0, 0, 0, 0};
    float w[8];
#pragma unroll
    for (int j = 0; j < 8; ++j) w[j] = up[SW(t0 + 1 + j)];
#pragma unroll 8
    for (int s = 255; s >= 1; --s) {
        float gv = gtap[s];
#pragma unroll
        for (int j = 0; j < 8; ++j) acc[j] = fmaf(gv, w[j], acc[j]);
#pragma unroll
        for (int j = 0; j < 7; ++j) w[j] = w[j + 1];
        w[7] = up[SW(FL + t0 + 8 - s)];
    }
    float g0 = gtap[0];
#pragma unroll
    for (int j = 0; j < 8; ++j) acc[j] = fmaf(g0, w[j], acc[j]);
    float4 o0 = make_float4(fmaf(gain, acc[0], rec_acc[0]),
                            fmaf(gain, acc[1], rec_acc[1]),
                            fmaf(gain, acc[2], rec_acc[2]),
                            fmaf(gain, acc[3], rec_acc[3]));
    float4 o1 = make_float4(fmaf(gain, acc[4], rec_acc[4]),
                            fmaf(gain, acc[5], rec_acc[5]),
                            fmaf(gain, acc[6], rec_acc[6]),
                            fmaf(gain, acc[7], rec_acc[7]));
    *(float4*)(out + HF_OFF + rowbase)     = o0;
    *(float4*)(out + HF_OFF + rowbase + 4) = o1;
}

extern "C" void kernel_launch(void* const* d_in, const int* in_sizes, int n_in,
                              void* d_out, int out_size, void* d_ws, size_t ws_size,
                              hipStream_t stream)
{
    const float* forces  = (const float*)d_in[0];
    const float* hm      = (const float*)d_in[1];
    const float* filters = (const float*)d_in[2];
    const float* home    = (const float*)d_in[3];
    const float* cs      = (const float*)d_in[4];
    const float* masses  = (const float*)d_in[5];
    const float* tens    = (const float*)d_in[6];
    const float* mics    = (const float*)d_in[7];
    const float* tfm     = (const float*)d_in[8];
    const float* bias    = (const float*)d_in[9];
    const float* gain    = (const float*)d_in[10];
    float* out = (float*)d_out;

    sim_all<<<BB * MM, 1024, 0, stream>>>(
        forces, hm, home, cs, masses, tens, mics,
        filters, tfm, bias, gain, out);
}